// Round 1
// baseline (3882.507 us; speedup 1.0000x reference)
//
#include <hip/hip_runtime.h>
#include <math.h>

// SGC 2-layer: out = A_hat * elu(A_hat * X * W1 + b1) * W2 + b2
// A_hat = D^-1/2 A D^-1/2 (in-degree based, clip(deg,1))
// Layer-2 optimization: matmul commutes with aggregation -> aggregate 40 dims not 128.

#define DIN  128
#define DHID 128
#define DOUT 40

__device__ __forceinline__ float elu_f(float x) {
    return x > 0.0f ? x : (expf(x) - 1.0f);
}

__global__ void deg_kernel(const int* __restrict__ dst, int E, float* __restrict__ deg) {
    int stride = gridDim.x * blockDim.x;
    for (int i = blockIdx.x * blockDim.x + threadIdx.x; i < E; i += stride)
        atomicAdd(&deg[dst[i]], 1.0f);
}

__global__ void norm_kernel(float* __restrict__ deg, int N) {
    int stride = gridDim.x * blockDim.x;
    for (int i = blockIdx.x * blockDim.x + threadIdx.x; i < N; i += stride)
        deg[i] = rsqrtf(fmaxf(deg[i], 1.0f));
}

// agg[dst] += feat[src] * norm[src], 32 threads per edge (4 floats each)
__global__ void scatter1_kernel(const float* __restrict__ feat, const int* __restrict__ src,
                                const int* __restrict__ dst, const float* __restrict__ norm,
                                float* __restrict__ agg, int E) {
    long T = (long)blockIdx.x * blockDim.x + threadIdx.x;
    int l4 = (int)(T & 31);
    long e = T >> 5;
    long estride = ((long)gridDim.x * blockDim.x) >> 5;
    for (; e < E; e += estride) {
        int s = src[e], d = dst[e];
        float ns = norm[s];
        float4 v = reinterpret_cast<const float4*>(feat)[(long)s * 32 + l4];
        float* o = agg + (long)d * DIN + l4 * 4;
        atomicAdd(o + 0, v.x * ns);
        atomicAdd(o + 1, v.y * ns);
        atomicAdd(o + 2, v.z * ns);
        atomicAdd(o + 3, v.w * ns);
    }
}

// h[n] = elu( (agg[n]*norm[n]) @ W1 + b1 ), in-place (xh both in and out).
// W1 fully in LDS (64KB); 32 rows/chunk staged in LDS; thread = 4 rows x 4 cols.
__launch_bounds__(256, 2)
__global__ void mm1_kernel(float* __restrict__ xh, const float* __restrict__ W1,
                           const float* __restrict__ b1, const float* __restrict__ norm,
                           int N) {
    __shared__ float Wl[DIN * DHID];   // 64KB
    __shared__ float Xl[32 * DIN];     // 16KB
    for (int i = threadIdx.x; i < DIN * DHID; i += 256) Wl[i] = W1[i];
    int cg = threadIdx.x & 31;   // col group -> cols cg*4..cg*4+3
    int rg = threadIdx.x >> 5;   // row group -> rows rg*4..rg*4+3 in chunk
    int c0 = cg * 4;
    for (long r0 = (long)blockIdx.x * 32; r0 < N; r0 += (long)gridDim.x * 32) {
        __syncthreads();
        // stage 32 rows, scaled by norm[row]
        for (int i = threadIdx.x; i < 32 * (DIN / 4); i += 256) {
            int rr = i >> 5;           // row in chunk (32 float4 per row)
            long row = r0 + rr;
            float4 v = make_float4(0.f, 0.f, 0.f, 0.f);
            if (row < N) {
                v = reinterpret_cast<const float4*>(xh)[row * 32 + (i & 31)];
                float nm = norm[row];
                v.x *= nm; v.y *= nm; v.z *= nm; v.w *= nm;
            }
            reinterpret_cast<float4*>(Xl)[i] = v;
        }
        __syncthreads();
        float acc[4][4];
        float bx = b1[c0], by = b1[c0 + 1], bz = b1[c0 + 2], bw = b1[c0 + 3];
        #pragma unroll
        for (int r = 0; r < 4; ++r) { acc[r][0] = bx; acc[r][1] = by; acc[r][2] = bz; acc[r][3] = bw; }
        for (int k = 0; k < DIN; k += 4) {
            float4 w0 = *reinterpret_cast<const float4*>(&Wl[(k + 0) * DHID + c0]);
            float4 w1 = *reinterpret_cast<const float4*>(&Wl[(k + 1) * DHID + c0]);
            float4 w2 = *reinterpret_cast<const float4*>(&Wl[(k + 2) * DHID + c0]);
            float4 w3 = *reinterpret_cast<const float4*>(&Wl[(k + 3) * DHID + c0]);
            #pragma unroll
            for (int r = 0; r < 4; ++r) {
                float4 x = *reinterpret_cast<const float4*>(&Xl[(rg * 4 + r) * DIN + k]);
                acc[r][0] = fmaf(x.x, w0.x, fmaf(x.y, w1.x, fmaf(x.z, w2.x, fmaf(x.w, w3.x, acc[r][0]))));
                acc[r][1] = fmaf(x.x, w0.y, fmaf(x.y, w1.y, fmaf(x.z, w2.y, fmaf(x.w, w3.y, acc[r][1]))));
                acc[r][2] = fmaf(x.x, w0.z, fmaf(x.y, w1.z, fmaf(x.z, w2.z, fmaf(x.w, w3.z, acc[r][2]))));
                acc[r][3] = fmaf(x.x, w0.w, fmaf(x.y, w1.w, fmaf(x.z, w2.w, fmaf(x.w, w3.w, acc[r][3]))));
            }
        }
        #pragma unroll
        for (int r = 0; r < 4; ++r) {
            long row = r0 + rg * 4 + r;
            if (row < N) {
                float4 o;
                o.x = elu_f(acc[r][0]); o.y = elu_f(acc[r][1]);
                o.z = elu_f(acc[r][2]); o.w = elu_f(acc[r][3]);
                *reinterpret_cast<float4*>(&xh[row * DIN + c0]) = o;
            }
        }
    }
}

// z[n] = norm[n] * (h[n] @ W2)   (bias deferred to final pass)
__launch_bounds__(256, 2)
__global__ void mm2_kernel(const float* __restrict__ h, const float* __restrict__ W2,
                           const float* __restrict__ norm, float* __restrict__ z, int N) {
    __shared__ float Wl[DHID * DOUT];  // 20KB
    __shared__ float Xl[64 * DIN];     // 32KB
    for (int i = threadIdx.x; i < DHID * DOUT; i += 256) Wl[i] = W2[i];
    int cg = threadIdx.x & 15;   // col group, active if cg < 10
    int rg = threadIdx.x >> 4;   // 0..15 -> rows rg*4..rg*4+3
    int c0 = cg * 4;
    for (long r0 = (long)blockIdx.x * 64; r0 < N; r0 += (long)gridDim.x * 64) {
        __syncthreads();
        for (int i = threadIdx.x; i < 64 * (DIN / 4); i += 256) {
            int rr = i >> 5;
            long row = r0 + rr;
            float4 v = make_float4(0.f, 0.f, 0.f, 0.f);
            if (row < N) v = reinterpret_cast<const float4*>(h)[row * 32 + (i & 31)];
            reinterpret_cast<float4*>(Xl)[i] = v;
        }
        __syncthreads();
        if (c0 < DOUT) {
            float acc[4][4];
            #pragma unroll
            for (int r = 0; r < 4; ++r) { acc[r][0] = 0.f; acc[r][1] = 0.f; acc[r][2] = 0.f; acc[r][3] = 0.f; }
            for (int k = 0; k < DHID; k += 4) {
                float4 w0 = *reinterpret_cast<const float4*>(&Wl[(k + 0) * DOUT + c0]);
                float4 w1 = *reinterpret_cast<const float4*>(&Wl[(k + 1) * DOUT + c0]);
                float4 w2 = *reinterpret_cast<const float4*>(&Wl[(k + 2) * DOUT + c0]);
                float4 w3 = *reinterpret_cast<const float4*>(&Wl[(k + 3) * DOUT + c0]);
                #pragma unroll
                for (int r = 0; r < 4; ++r) {
                    float4 x = *reinterpret_cast<const float4*>(&Xl[(rg * 4 + r) * DIN + k]);
                    acc[r][0] = fmaf(x.x, w0.x, fmaf(x.y, w1.x, fmaf(x.z, w2.x, fmaf(x.w, w3.x, acc[r][0]))));
                    acc[r][1] = fmaf(x.x, w0.y, fmaf(x.y, w1.y, fmaf(x.z, w2.y, fmaf(x.w, w3.y, acc[r][1]))));
                    acc[r][2] = fmaf(x.x, w0.z, fmaf(x.y, w1.z, fmaf(x.z, w2.z, fmaf(x.w, w3.z, acc[r][2]))));
                    acc[r][3] = fmaf(x.x, w0.w, fmaf(x.y, w1.w, fmaf(x.z, w2.w, fmaf(x.w, w3.w, acc[r][3]))));
                }
            }
            #pragma unroll
            for (int r = 0; r < 4; ++r) {
                long row = r0 + rg * 4 + r;
                if (row < N) {
                    float nm = norm[row];
                    float4 o;
                    o.x = acc[r][0] * nm; o.y = acc[r][1] * nm;
                    o.z = acc[r][2] * nm; o.w = acc[r][3] * nm;
                    *reinterpret_cast<float4*>(&z[row * DOUT + c0]) = o;
                }
            }
        }
    }
}

// out[dst] += z[src], 16 threads per edge (10 active, float4 each)
__global__ void scatter2_kernel(const float* __restrict__ z, const int* __restrict__ src,
                                const int* __restrict__ dst, float* __restrict__ out, int E) {
    long T = (long)blockIdx.x * blockDim.x + threadIdx.x;
    int l = (int)(T & 15);
    long e = T >> 4;
    long estride = ((long)gridDim.x * blockDim.x) >> 4;
    for (; e < E; e += estride) {
        if (l < 10) {
            int s = src[e], d = dst[e];
            float4 v = reinterpret_cast<const float4*>(z)[(long)s * 10 + l];
            float* o = out + (long)d * DOUT + l * 4;
            atomicAdd(o + 0, v.x);
            atomicAdd(o + 1, v.y);
            atomicAdd(o + 2, v.z);
            atomicAdd(o + 3, v.w);
        }
    }
}

// out = out * norm[n] + b2[d]
__global__ void final_kernel(float* __restrict__ out, const float* __restrict__ norm,
                             const float* __restrict__ b2, int N) {
    long total = (long)N * DOUT;
    long stride = (long)gridDim.x * blockDim.x;
    for (long i = (long)blockIdx.x * blockDim.x + threadIdx.x; i < total; i += stride) {
        int n = (int)(i / DOUT), d = (int)(i % DOUT);
        out[i] = fmaf(out[i], norm[n], b2[d]);
    }
}

extern "C" void kernel_launch(void* const* d_in, const int* in_sizes, int n_in,
                              void* d_out, int out_size, void* d_ws, size_t ws_size,
                              hipStream_t stream) {
    const float* feat = (const float*)d_in[0];
    const int*   src  = (const int*)d_in[1];
    const int*   dst  = (const int*)d_in[2];
    const float* W1   = (const float*)d_in[3];
    const float* b1   = (const float*)d_in[4];
    const float* W2   = (const float*)d_in[5];
    const float* b2   = (const float*)d_in[6];
    int N = in_sizes[0] / DIN;
    int E = in_sizes[1];
    float* out = (float*)d_out;

    char* ws = (char*)d_ws;
    size_t off = 0;
    float* norm = (float*)(ws + off);
    off += (((size_t)N * 4) + 4095) & ~(size_t)4095;
    float* agg1 = (float*)(ws + off);                 // N x 128, reused in-place for h
    off += (((size_t)N * DIN * 4) + 4095) & ~(size_t)4095;
    float* z = (float*)(ws + off);                    // N x 40

    hipMemsetAsync(norm, 0, (size_t)N * 4, stream);
    hipMemsetAsync(agg1, 0, (size_t)N * DIN * 4, stream);
    hipMemsetAsync(d_out, 0, (size_t)N * DOUT * 4, stream);

    deg_kernel<<<1024, 256, 0, stream>>>(dst, E, norm);
    norm_kernel<<<(N + 255) / 256, 256, 0, stream>>>(norm, N);
    scatter1_kernel<<<4096, 256, 0, stream>>>(feat, src, dst, norm, agg1, E);
    mm1_kernel<<<(N + 31) / 32, 256, 0, stream>>>(agg1, W1, b1, norm, N);
    mm2_kernel<<<(N + 63) / 64, 256, 0, stream>>>(agg1, W2, norm, z, N);
    scatter2_kernel<<<4096, 256, 0, stream>>>(z, src, dst, out, E);
    final_kernel<<<4096, 256, 0, stream>>>(out, norm, b2, N);
}

// Round 2
// 489.200 us; speedup vs baseline: 7.9364x; 7.9364x over previous
//
#include <hip/hip_runtime.h>
#include <math.h>

// SGC 2-layer: out = A_hat * elu(A_hat * X * W1 + b1) * W2 + b2
// A_hat = D^-1/2 A D^-1/2 (in-degree based, clip(deg,1))
// R2: replace float-atomic scatter (204.8M atomics, 2.7ms) with CSR build +
// register-accumulating gather. Layer-2 still aggregates 40 dims (matmul first).

#define DIN  128
#define DHID 128
#define DOUT 40

__device__ __forceinline__ float elu_f(float x) {
    return x > 0.0f ? x : (expf(x) - 1.0f);
}

// ---------------- CSR build ----------------

__global__ void degi_kernel(const int* __restrict__ dst, int E, int* __restrict__ deg) {
    int stride = gridDim.x * blockDim.x;
    for (int i = blockIdx.x * blockDim.x + threadIdx.x; i < E; i += stride)
        atomicAdd(&deg[dst[i]], 1);
}

__global__ void norm_from_deg(const int* __restrict__ deg, float* __restrict__ norm, int N) {
    int stride = gridDim.x * blockDim.x;
    for (int i = blockIdx.x * blockDim.x + threadIdx.x; i < N; i += stride)
        norm[i] = rsqrtf(fmaxf((float)deg[i], 1.0f));
}

__global__ void scan_partial(const int* __restrict__ deg, int N, int* __restrict__ bsum) {
    __shared__ int sd[256];
    int i = blockIdx.x * 256 + threadIdx.x;
    sd[threadIdx.x] = (i < N) ? deg[i] : 0;
    __syncthreads();
    for (int s = 128; s > 0; s >>= 1) {
        if (threadIdx.x < s) sd[threadIdx.x] += sd[threadIdx.x + s];
        __syncthreads();
    }
    if (threadIdx.x == 0) bsum[blockIdx.x] = sd[0];
}

__global__ void scan_bsum(int* __restrict__ bsum, int nb) {
    if (blockIdx.x == 0 && threadIdx.x == 0) {
        int acc = 0;
        for (int b = 0; b < nb; ++b) { int v = bsum[b]; bsum[b] = acc; acc += v; }
    }
}

__global__ void scan_final(const int* __restrict__ deg, int N, int E,
                           const int* __restrict__ bsum, int* __restrict__ rowptr) {
    __shared__ int sd[256];
    int tid = threadIdx.x;
    int i = blockIdx.x * 256 + tid;
    int v = (i < N) ? deg[i] : 0;
    sd[tid] = v;
    __syncthreads();
    for (int off = 1; off < 256; off <<= 1) {
        int t = (tid >= off) ? sd[tid - off] : 0;
        __syncthreads();
        sd[tid] += t;
        __syncthreads();
    }
    if (i < N) rowptr[i] = bsum[blockIdx.x] + sd[tid] - v;
    if (i == 0) rowptr[N] = E;
}

__global__ void fill_kernel(const int* __restrict__ src, const int* __restrict__ dst,
                            const int* __restrict__ rowptr, int* __restrict__ cursor,
                            int* __restrict__ esrc, int E) {
    int stride = gridDim.x * blockDim.x;
    for (int e = blockIdx.x * blockDim.x + threadIdx.x; e < E; e += stride) {
        int d = dst[e];
        int pos = rowptr[d] + atomicAdd(&cursor[d], 1);
        esrc[pos] = src[e];
    }
}

// ---------------- gather aggregation ----------------

// agg[n] = sum_{j in rowptr[n]..rowptr[n+1]} feat[esrc[j]] * norm[esrc[j]]
// 32 lanes per node, float4 per lane.
__global__ void gather1_kernel(const float* __restrict__ feat, const float* __restrict__ norm,
                               const int* __restrict__ rowptr, const int* __restrict__ esrc,
                               float* __restrict__ agg, int N) {
    int lane = threadIdx.x & 31;
    long g = ((long)blockIdx.x * blockDim.x + threadIdx.x) >> 5;
    long gstride = ((long)gridDim.x * blockDim.x) >> 5;
    const float4* f4 = reinterpret_cast<const float4*>(feat);
    for (long n = g; n < N; n += gstride) {
        int beg = rowptr[n], end = rowptr[n + 1];
        float4 acc = make_float4(0.f, 0.f, 0.f, 0.f);
        int j = beg;
        for (; j + 1 < end; j += 2) {
            int s0 = esrc[j], s1 = esrc[j + 1];
            float n0 = norm[s0], n1 = norm[s1];
            float4 v0 = f4[(long)s0 * 32 + lane];
            float4 v1 = f4[(long)s1 * 32 + lane];
            acc.x = fmaf(v0.x, n0, acc.x); acc.y = fmaf(v0.y, n0, acc.y);
            acc.z = fmaf(v0.z, n0, acc.z); acc.w = fmaf(v0.w, n0, acc.w);
            acc.x = fmaf(v1.x, n1, acc.x); acc.y = fmaf(v1.y, n1, acc.y);
            acc.z = fmaf(v1.z, n1, acc.z); acc.w = fmaf(v1.w, n1, acc.w);
        }
        if (j < end) {
            int s0 = esrc[j];
            float n0 = norm[s0];
            float4 v0 = f4[(long)s0 * 32 + lane];
            acc.x = fmaf(v0.x, n0, acc.x); acc.y = fmaf(v0.y, n0, acc.y);
            acc.z = fmaf(v0.z, n0, acc.z); acc.w = fmaf(v0.w, n0, acc.w);
        }
        reinterpret_cast<float4*>(agg)[n * 32 + lane] = acc;
    }
}

// out[n] = norm[n] * sum_j z[esrc[j]] + b2   (16 lanes per node, 10 active)
__global__ void gather2_kernel(const float* __restrict__ z, const int* __restrict__ rowptr,
                               const int* __restrict__ esrc, const float* __restrict__ norm,
                               const float* __restrict__ b2, float* __restrict__ out, int N) {
    int lane = threadIdx.x & 15;
    long g = ((long)blockIdx.x * blockDim.x + threadIdx.x) >> 4;
    long gstride = ((long)gridDim.x * blockDim.x) >> 4;
    const float4* z4 = reinterpret_cast<const float4*>(z);
    for (long n = g; n < N; n += gstride) {
        if (lane < 10) {
            int beg = rowptr[n], end = rowptr[n + 1];
            float4 acc = make_float4(0.f, 0.f, 0.f, 0.f);
            int j = beg;
            for (; j + 1 < end; j += 2) {
                int s0 = esrc[j], s1 = esrc[j + 1];
                float4 v0 = z4[(long)s0 * 10 + lane];
                float4 v1 = z4[(long)s1 * 10 + lane];
                acc.x += v0.x + v1.x; acc.y += v0.y + v1.y;
                acc.z += v0.z + v1.z; acc.w += v0.w + v1.w;
            }
            if (j < end) {
                int s0 = esrc[j];
                float4 v0 = z4[(long)s0 * 10 + lane];
                acc.x += v0.x; acc.y += v0.y; acc.z += v0.z; acc.w += v0.w;
            }
            float nm = norm[n];
            float4 bb = reinterpret_cast<const float4*>(b2)[lane];
            float4 o;
            o.x = fmaf(acc.x, nm, bb.x); o.y = fmaf(acc.y, nm, bb.y);
            o.z = fmaf(acc.z, nm, bb.z); o.w = fmaf(acc.w, nm, bb.w);
            reinterpret_cast<float4*>(out)[n * 10 + lane] = o;
        }
    }
}

// ---------------- dense matmuls ----------------

// h[n] = elu( (agg[n]*norm[n]) @ W1 + b1 ), in-place.
__launch_bounds__(256, 2)
__global__ void mm1_kernel(float* __restrict__ xh, const float* __restrict__ W1,
                           const float* __restrict__ b1, const float* __restrict__ norm,
                           int N) {
    __shared__ float Wl[DIN * DHID];   // 64KB
    __shared__ float Xl[32 * DIN];     // 16KB
    for (int i = threadIdx.x; i < DIN * DHID; i += 256) Wl[i] = W1[i];
    int cg = threadIdx.x & 31;
    int rg = threadIdx.x >> 5;
    int c0 = cg * 4;
    for (long r0 = (long)blockIdx.x * 32; r0 < N; r0 += (long)gridDim.x * 32) {
        __syncthreads();
        for (int i = threadIdx.x; i < 32 * (DIN / 4); i += 256) {
            int rr = i >> 5;
            long row = r0 + rr;
            float4 v = make_float4(0.f, 0.f, 0.f, 0.f);
            if (row < N) {
                v = reinterpret_cast<const float4*>(xh)[row * 32 + (i & 31)];
                float nm = norm[row];
                v.x *= nm; v.y *= nm; v.z *= nm; v.w *= nm;
            }
            reinterpret_cast<float4*>(Xl)[i] = v;
        }
        __syncthreads();
        float acc[4][4];
        float bx = b1[c0], by = b1[c0 + 1], bz = b1[c0 + 2], bw = b1[c0 + 3];
        #pragma unroll
        for (int r = 0; r < 4; ++r) { acc[r][0] = bx; acc[r][1] = by; acc[r][2] = bz; acc[r][3] = bw; }
        for (int k = 0; k < DIN; k += 4) {
            float4 w0 = *reinterpret_cast<const float4*>(&Wl[(k + 0) * DHID + c0]);
            float4 w1 = *reinterpret_cast<const float4*>(&Wl[(k + 1) * DHID + c0]);
            float4 w2 = *reinterpret_cast<const float4*>(&Wl[(k + 2) * DHID + c0]);
            float4 w3 = *reinterpret_cast<const float4*>(&Wl[(k + 3) * DHID + c0]);
            #pragma unroll
            for (int r = 0; r < 4; ++r) {
                float4 x = *reinterpret_cast<const float4*>(&Xl[(rg * 4 + r) * DIN + k]);
                acc[r][0] = fmaf(x.x, w0.x, fmaf(x.y, w1.x, fmaf(x.z, w2.x, fmaf(x.w, w3.x, acc[r][0]))));
                acc[r][1] = fmaf(x.x, w0.y, fmaf(x.y, w1.y, fmaf(x.z, w2.y, fmaf(x.w, w3.y, acc[r][1]))));
                acc[r][2] = fmaf(x.x, w0.z, fmaf(x.y, w1.z, fmaf(x.z, w2.z, fmaf(x.w, w3.z, acc[r][2]))));
                acc[r][3] = fmaf(x.x, w0.w, fmaf(x.y, w1.w, fmaf(x.z, w2.w, fmaf(x.w, w3.w, acc[r][3]))));
            }
        }
        #pragma unroll
        for (int r = 0; r < 4; ++r) {
            long row = r0 + rg * 4 + r;
            if (row < N) {
                float4 o;
                o.x = elu_f(acc[r][0]); o.y = elu_f(acc[r][1]);
                o.z = elu_f(acc[r][2]); o.w = elu_f(acc[r][3]);
                *reinterpret_cast<float4*>(&xh[row * DIN + c0]) = o;
            }
        }
    }
}

// z[n] = norm[n] * (h[n] @ W2)
__launch_bounds__(256, 2)
__global__ void mm2_kernel(const float* __restrict__ h, const float* __restrict__ W2,
                           const float* __restrict__ norm, float* __restrict__ z, int N) {
    __shared__ float Wl[DHID * DOUT];
    __shared__ float Xl[64 * DIN];
    for (int i = threadIdx.x; i < DHID * DOUT; i += 256) Wl[i] = W2[i];
    int cg = threadIdx.x & 15;
    int rg = threadIdx.x >> 4;
    int c0 = cg * 4;
    for (long r0 = (long)blockIdx.x * 64; r0 < N; r0 += (long)gridDim.x * 64) {
        __syncthreads();
        for (int i = threadIdx.x; i < 64 * (DIN / 4); i += 256) {
            int rr = i >> 5;
            long row = r0 + rr;
            float4 v = make_float4(0.f, 0.f, 0.f, 0.f);
            if (row < N) v = reinterpret_cast<const float4*>(h)[row * 32 + (i & 31)];
            reinterpret_cast<float4*>(Xl)[i] = v;
        }
        __syncthreads();
        if (c0 < DOUT) {
            float acc[4][4];
            #pragma unroll
            for (int r = 0; r < 4; ++r) { acc[r][0] = 0.f; acc[r][1] = 0.f; acc[r][2] = 0.f; acc[r][3] = 0.f; }
            for (int k = 0; k < DHID; k += 4) {
                float4 w0 = *reinterpret_cast<const float4*>(&Wl[(k + 0) * DOUT + c0]);
                float4 w1 = *reinterpret_cast<const float4*>(&Wl[(k + 1) * DOUT + c0]);
                float4 w2 = *reinterpret_cast<const float4*>(&Wl[(k + 2) * DOUT + c0]);
                float4 w3 = *reinterpret_cast<const float4*>(&Wl[(k + 3) * DOUT + c0]);
                #pragma unroll
                for (int r = 0; r < 4; ++r) {
                    float4 x = *reinterpret_cast<const float4*>(&Xl[(rg * 4 + r) * DIN + k]);
                    acc[r][0] = fmaf(x.x, w0.x, fmaf(x.y, w1.x, fmaf(x.z, w2.x, fmaf(x.w, w3.x, acc[r][0]))));
                    acc[r][1] = fmaf(x.x, w0.y, fmaf(x.y, w1.y, fmaf(x.z, w2.y, fmaf(x.w, w3.y, acc[r][1]))));
                    acc[r][2] = fmaf(x.x, w0.z, fmaf(x.y, w1.z, fmaf(x.z, w2.z, fmaf(x.w, w3.z, acc[r][2]))));
                    acc[r][3] = fmaf(x.x, w0.w, fmaf(x.y, w1.w, fmaf(x.z, w2.w, fmaf(x.w, w3.w, acc[r][3]))));
                }
            }
            #pragma unroll
            for (int r = 0; r < 4; ++r) {
                long row = r0 + rg * 4 + r;
                if (row < N) {
                    float nm = norm[row];
                    float4 o;
                    o.x = acc[r][0] * nm; o.y = acc[r][1] * nm;
                    o.z = acc[r][2] * nm; o.w = acc[r][3] * nm;
                    *reinterpret_cast<float4*>(&z[row * DOUT + c0]) = o;
                }
            }
        }
    }
}

// ---------------- fallback (R1 atomic path) ----------------

__global__ void scatter1_kernel(const float* __restrict__ feat, const int* __restrict__ src,
                                const int* __restrict__ dst, const float* __restrict__ norm,
                                float* __restrict__ agg, int E) {
    long T = (long)blockIdx.x * blockDim.x + threadIdx.x;
    int l4 = (int)(T & 31);
    long e = T >> 5;
    long estride = ((long)gridDim.x * blockDim.x) >> 5;
    for (; e < E; e += estride) {
        int s = src[e], d = dst[e];
        float ns = norm[s];
        float4 v = reinterpret_cast<const float4*>(feat)[(long)s * 32 + l4];
        float* o = agg + (long)d * DIN + l4 * 4;
        atomicAdd(o + 0, v.x * ns);
        atomicAdd(o + 1, v.y * ns);
        atomicAdd(o + 2, v.z * ns);
        atomicAdd(o + 3, v.w * ns);
    }
}

__global__ void scatter2_kernel(const float* __restrict__ z, const int* __restrict__ src,
                                const int* __restrict__ dst, float* __restrict__ out, int E) {
    long T = (long)blockIdx.x * blockDim.x + threadIdx.x;
    int l = (int)(T & 15);
    long e = T >> 4;
    long estride = ((long)gridDim.x * blockDim.x) >> 4;
    for (; e < E; e += estride) {
        if (l < 10) {
            int s = src[e], d = dst[e];
            float4 v = reinterpret_cast<const float4*>(z)[(long)s * 10 + l];
            float* o = out + (long)d * DOUT + l * 4;
            atomicAdd(o + 0, v.x);
            atomicAdd(o + 1, v.y);
            atomicAdd(o + 2, v.z);
            atomicAdd(o + 3, v.w);
        }
    }
}

__global__ void final_kernel(float* __restrict__ out, const float* __restrict__ norm,
                             const float* __restrict__ b2, int N) {
    long total = (long)N * DOUT;
    long stride = (long)gridDim.x * blockDim.x;
    for (long i = (long)blockIdx.x * blockDim.x + threadIdx.x; i < total; i += stride) {
        int n = (int)(i / DOUT), d = (int)(i % DOUT);
        out[i] = fmaf(out[i], norm[n], b2[d]);
    }
}

// ---------------- launch ----------------

static inline size_t al4k(size_t x) { return (x + 4095) & ~(size_t)4095; }

extern "C" void kernel_launch(void* const* d_in, const int* in_sizes, int n_in,
                              void* d_out, int out_size, void* d_ws, size_t ws_size,
                              hipStream_t stream) {
    const float* feat = (const float*)d_in[0];
    const int*   src  = (const int*)d_in[1];
    const int*   dst  = (const int*)d_in[2];
    const float* W1   = (const float*)d_in[3];
    const float* b1   = (const float*)d_in[4];
    const float* W2   = (const float*)d_in[5];
    const float* b2   = (const float*)d_in[6];
    int N = in_sizes[0] / DIN;
    int E = in_sizes[1];
    float* out = (float*)d_out;
    char* ws = (char*)d_ws;

    int nb = (N + 255) / 256;

    // CSR-path workspace layout
    size_t o_norm   = 0;
    size_t o_degi   = o_norm   + al4k((size_t)N * 4);
    size_t o_cursor = o_degi   + al4k((size_t)N * 4);
    size_t o_rowptr = o_cursor + al4k((size_t)N * 4);
    size_t o_bsum   = o_rowptr + al4k(((size_t)N + 1) * 4);
    size_t o_esrc   = o_bsum   + al4k((size_t)nb * 4);
    size_t o_agg    = o_esrc   + al4k((size_t)E * 4);
    size_t o_z      = o_agg    + al4k((size_t)N * DIN * 4);
    size_t need     = o_z      + al4k((size_t)N * DOUT * 4);

    if (ws_size >= need) {
        float* norm   = (float*)(ws + o_norm);
        int*   degi   = (int*)(ws + o_degi);
        int*   cursor = (int*)(ws + o_cursor);
        int*   rowptr = (int*)(ws + o_rowptr);
        int*   bsum   = (int*)(ws + o_bsum);
        int*   esrc   = (int*)(ws + o_esrc);
        float* agg    = (float*)(ws + o_agg);
        float* z      = (float*)(ws + o_z);

        hipMemsetAsync(degi, 0, (size_t)N * 4, stream);
        hipMemsetAsync(cursor, 0, (size_t)N * 4, stream);

        degi_kernel<<<2048, 256, 0, stream>>>(dst, E, degi);
        scan_partial<<<nb, 256, 0, stream>>>(degi, N, bsum);
        scan_bsum<<<1, 1, 0, stream>>>(bsum, nb);
        scan_final<<<nb, 256, 0, stream>>>(degi, N, E, bsum, rowptr);
        norm_from_deg<<<(N + 255) / 256, 256, 0, stream>>>(degi, norm, N);
        fill_kernel<<<2048, 256, 0, stream>>>(src, dst, rowptr, cursor, esrc, E);

        gather1_kernel<<<(N * 32 + 255) / 256, 256, 0, stream>>>(feat, norm, rowptr, esrc, agg, N);
        mm1_kernel<<<(N + 31) / 32, 256, 0, stream>>>(agg, W1, b1, norm, N);
        mm2_kernel<<<(N + 63) / 64, 256, 0, stream>>>(agg, W2, norm, z, N);
        gather2_kernel<<<(N * 16 + 255) / 256, 256, 0, stream>>>(z, rowptr, esrc, norm, b2, out, N);
    } else {
        // fallback: R1 atomic-scatter path (fits in 67.6MB)
        size_t f_norm = 0;
        size_t f_agg  = f_norm + al4k((size_t)N * 4);
        size_t f_z    = f_agg  + al4k((size_t)N * DIN * 4);
        float* norm = (float*)(ws + f_norm);
        float* agg  = (float*)(ws + f_agg);
        float* z    = (float*)(ws + f_z);
        int*   degi = (int*)(ws + f_norm);  // reuse norm buffer for int degrees first

        hipMemsetAsync(degi, 0, (size_t)N * 4, stream);
        hipMemsetAsync(agg, 0, (size_t)N * DIN * 4, stream);
        hipMemsetAsync(d_out, 0, (size_t)N * DOUT * 4, stream);

        degi_kernel<<<1024, 256, 0, stream>>>(dst, E, degi);
        norm_from_deg<<<(N + 255) / 256, 256, 0, stream>>>(degi, (float*)degi, N);
        scatter1_kernel<<<4096, 256, 0, stream>>>(feat, src, dst, norm, agg, E);
        mm1_kernel<<<(N + 31) / 32, 256, 0, stream>>>(agg, W1, b1, norm, N);
        mm2_kernel<<<(N + 63) / 64, 256, 0, stream>>>(agg, W2, norm, z, N);
        scatter2_kernel<<<4096, 256, 0, stream>>>(z, src, dst, out, E);
        final_kernel<<<4096, 256, 0, stream>>>(out, norm, b2, N);
    }
}